// Round 8
// baseline (256.652 us; speedup 1.0000x reference)
//
#include <hip/hip_runtime.h>
#include <hip/hip_bf16.h>

#define BATCH 2048
#define NNODES 512
#define HID 64
#define LN_EPS 1e-5f
#define NEG_SLOPE 0.01f

#define NPB 4        // nodes per block (one per wave)
#define RPB 32       // batch rows per block (2 sub-tiles of 16)
#define SUBS 2
#define TSTR 68      // LDS t-row stride in floats (68 mod 32 = 4: balanced banks)

typedef __attribute__((ext_vector_type(8))) short bf16x8;
typedef __attribute__((ext_vector_type(4))) float f32x4;

__device__ __forceinline__ short f2bf(float f) {
    union { __hip_bfloat16 h; short s; } u;
    u.h = __float2bfloat16(f);   // canonical RNE (R3/R4-verified)
    return u.s;
}

// R6 body verbatim; ONLY change vs R6: __launch_bounds__(256, 8) -> 8
// blocks/CU co-resident (VGPR 52 <= 64 cap, LDS 17.9KB*8 = 143KB <= 160KB).
// Grid is ng-minor (R6/R7 A/B proved this is worth ~2x: concurrent blocks
// span all nodes at one row chunk -> contiguous DRAM spans for x and out).
__global__ __launch_bounds__(256, 8) void wv_mfma6_kernel(
    const float* __restrict__ x,      // [B, N, H]
    const float* __restrict__ dec,    // [3, 4]
    const float* __restrict__ rec,    // [3, 4]
    const float* __restrict__ W,      // [N, H, H]
    const float* __restrict__ bias,   // [N, H]
    const float* __restrict__ gamma,  // [N, H]
    const float* __restrict__ beta,   // [N, H]
    const int*   __restrict__ scales, // [N]
    float* __restrict__ out)          // [B, N, H]
{
    __shared__ float tLds [NPB][16][TSTR];
    __shared__ float muLds[NPB][16];
    __shared__ float rsLds[NPB][16];

    const int tid  = threadIdx.x;
    const int wave = tid >> 6;
    const int lane = tid & 63;
    const int l16  = lane & 15;
    const int lg   = lane >> 4;      // 0..3

    const int ng   = blockIdx.x & 127;   // node group (minor: adjacent blocks = adjacent nodes)
    const int rc   = blockIdx.x >> 7;    // 0..63 row chunk
    const int node = ng * NPB + wave;
    const int b0   = rc * RPB;

    const int   sc   = scales[node];
    const float sfac = dec[sc * 4 + 1] + rec[sc * 4 + 1];

    // ---- W fragments (first mfma operand; R4-verified layout):
    //      lane holds W[node][c*16+l16][s*32 + lg*8 + j]
    bf16x8 wf[4][2];
    const float* Wn = W + (size_t)node * HID * HID;
    #pragma unroll
    for (int c = 0; c < 4; ++c) {
        #pragma unroll
        for (int s = 0; s < 2; ++s) {
            const float* p = Wn + (c * 16 + l16) * HID + s * 32 + lg * 8;
            f32x4 w0 = *reinterpret_cast<const f32x4*>(p);
            f32x4 w1 = *reinterpret_cast<const f32x4*>(p + 4);
            bf16x8 f;
            f[0] = f2bf(w0[0]); f[1] = f2bf(w0[1]); f[2] = f2bf(w0[2]); f[3] = f2bf(w0[3]);
            f[4] = f2bf(w1[0]); f[5] = f2bf(w1[1]); f[6] = f2bf(w1[2]); f[7] = f2bf(w1[3]);
            wf[c][s] = f;
        }
    }

    // ---- bias for MFMA-layout cols c*16 + lg*4 .. +3
    f32x4 bb[4];
    #pragma unroll
    for (int c = 0; c < 4; ++c)
        bb[c] = *reinterpret_cast<const f32x4*>(bias + node * HID + c * 16 + lg * 4);

    // ---- gamma/beta for epilogue-layout cols l16*4 .. +3
    const f32x4 gg = *reinterpret_cast<const f32x4*>(gamma + node * HID + l16 * 4);
    const f32x4 be = *reinterpret_cast<const f32x4*>(beta  + node * HID + l16 * 4);

    #pragma unroll
    for (int sub = 0; sub < SUBS; ++sub) {
        const int rowb = b0 + sub * 16;
        const int row  = rowb + l16;     // this lane's batch row in MFMA phase

        // ---- x fragments: 32B contiguous per lane per s-half
        const float* p = x + ((size_t)row * NNODES + node) * HID + lg * 8;
        f32x4 x0 = *reinterpret_cast<const f32x4*>(p);
        f32x4 x1 = *reinterpret_cast<const f32x4*>(p + 4);
        f32x4 x2 = *reinterpret_cast<const f32x4*>(p + 32);
        f32x4 x3 = *reinterpret_cast<const f32x4*>(p + 36);

        bf16x8 af0, af1;
        af0[0] = f2bf(x0[0] * sfac); af0[1] = f2bf(x0[1] * sfac);
        af0[2] = f2bf(x0[2] * sfac); af0[3] = f2bf(x0[3] * sfac);
        af0[4] = f2bf(x1[0] * sfac); af0[5] = f2bf(x1[1] * sfac);
        af0[6] = f2bf(x1[2] * sfac); af0[7] = f2bf(x1[3] * sfac);
        af1[0] = f2bf(x2[0] * sfac); af1[1] = f2bf(x2[1] * sfac);
        af1[2] = f2bf(x2[2] * sfac); af1[3] = f2bf(x2[3] * sfac);
        af1[4] = f2bf(x3[0] * sfac); af1[5] = f2bf(x3[1] * sfac);
        af1[6] = f2bf(x3[2] * sfac); af1[7] = f2bf(x3[3] * sfac);

        f32x4 acc[4];
        #pragma unroll
        for (int c = 0; c < 4; ++c) {
            acc[c][0] = 0.f; acc[c][1] = 0.f; acc[c][2] = 0.f; acc[c][3] = 0.f;
            acc[c] = __builtin_amdgcn_mfma_f32_16x16x32_bf16(wf[c][0], af0, acc[c], 0, 0, 0);
            acc[c] = __builtin_amdgcn_mfma_f32_16x16x32_bf16(wf[c][1], af1, acc[c], 0, 0, 0);
        }

        // ---- +bias and two-pass LN stats in registers (R4/R6-verified)
        float pS = 0.f;
        #pragma unroll
        for (int c = 0; c < 4; ++c) {
            #pragma unroll
            for (int i = 0; i < 4; ++i) {
                acc[c][i] += bb[c][i];
                pS += acc[c][i];
            }
        }
        pS += __shfl_xor(pS, 16, 64);
        pS += __shfl_xor(pS, 32, 64);
        const float mu = pS * (1.0f / 64.0f);

        float qS = 0.f;
        #pragma unroll
        for (int c = 0; c < 4; ++c) {
            #pragma unroll
            for (int i = 0; i < 4; ++i) {
                const float d = acc[c][i] - mu;
                qS += d * d;
            }
        }
        qS += __shfl_xor(qS, 16, 64);
        qS += __shfl_xor(qS, 32, 64);
        const float rstd = 1.0f / sqrtf(qS * (1.0f / 64.0f) + LN_EPS);

        // ---- repack t through wave-private LDS (no cross-wave -> no barrier)
        #pragma unroll
        for (int c = 0; c < 4; ++c)
            *reinterpret_cast<f32x4*>(&tLds[wave][l16][c * 16 + lg * 4]) = acc[c];
        if (lg == 0) { muLds[wave][l16] = mu; rsLds[wave][l16] = rstd; }

        // ---- epilogue: lane (l16,lg) -> row k*4+lg, cols l16*4..+3
        #pragma unroll
        for (int k = 0; k < 4; ++k) {
            const int rl = k * 4 + lg;
            f32x4 tv = *reinterpret_cast<const f32x4*>(&tLds[wave][rl][l16 * 4]);
            const float m  = muLds[wave][rl];
            const float rs = rsLds[wave][rl];
            f32x4 o;
            #pragma unroll
            for (int i = 0; i < 4; ++i) {
                float v = (tv[i] - m) * rs * gg[i] + be[i];
                o[i] = v >= 0.f ? v : v * NEG_SLOPE;
            }
            __builtin_nontemporal_store(
                o, reinterpret_cast<f32x4*>(
                       out + ((size_t)(rowb + rl) * NNODES + node) * HID + l16 * 4));
        }
    }
}

extern "C" void kernel_launch(void* const* d_in, const int* in_sizes, int n_in,
                              void* d_out, int out_size, void* d_ws, size_t ws_size,
                              hipStream_t stream) {
    const float* x      = (const float*)d_in[0];
    const float* dec    = (const float*)d_in[1];
    const float* rec    = (const float*)d_in[2];
    const float* W      = (const float*)d_in[3];
    const float* bias   = (const float*)d_in[4];
    const float* gamma  = (const float*)d_in[5];
    const float* beta   = (const float*)d_in[6];
    const int*   scales = (const int*)d_in[7];
    float* out = (float*)d_out;

    const int blocks = (NNODES / NPB) * (BATCH / RPB);  // 128 * 64 = 8192
    wv_mfma6_kernel<<<blocks, 256, 0, stream>>>(
        x, dec, rec, W, bias, gamma, beta, scales, out);
}

// Round 9
// 209.958 us; speedup vs baseline: 1.2224x; 1.2224x over previous
//
#include <hip/hip_runtime.h>
#include <hip/hip_bf16.h>

#define BATCH 2048
#define NNODES 512
#define HID 64
#define LN_EPS 1e-5f
#define NEG_SLOPE 0.01f

#define NPB 4        // nodes per block (one per wave)
#define SUBS 4       // 16-row MFMA tiles per wave
#define RPB 64       // rows per block = SUBS*16
#define TSTR 68      // LDS t-row stride in floats

typedef __attribute__((ext_vector_type(8))) short bf16x8;
typedef __attribute__((ext_vector_type(4))) float f32x4;

__device__ __forceinline__ short f2bf(float f) {
    union { __hip_bfloat16 h; short s; } u;
    u.h = __float2bfloat16(f);   // canonical RNE (R3/R4-verified)
    return u.s;
}

#define KEEP(v) asm volatile("" :: "v"(v))

// R6 epilogue/grid/NT-stores verbatim. Changes vs R6 (121.7us best):
//  - 64 rows/block (SUBS=4): W load+convert amortized 2x, W L2 traffic halved
//  - ALL x loads (16 dwordx4/lane) issued upfront, W-convert overlaps their
//    latency (vmcnt in-order), KEEP pins prevent the R5-style load sinking
//  - launch_bounds(256,4): 128-VGPR cap, ~100 needed -> no spill (R8 lesson:
//    never cap below need; (256,8)->32 VGPR spilled 700MB of scratch)
// Grid stays ng-minor (R7 lesson: rc-minor write-scatter costs 2x).
__global__ __launch_bounds__(256, 4) void wv_mfma7_kernel(
    const float* __restrict__ x,      // [B, N, H]
    const float* __restrict__ dec,    // [3, 4]
    const float* __restrict__ rec,    // [3, 4]
    const float* __restrict__ W,      // [N, H, H]
    const float* __restrict__ bias,   // [N, H]
    const float* __restrict__ gamma,  // [N, H]
    const float* __restrict__ beta,   // [N, H]
    const int*   __restrict__ scales, // [N]
    float* __restrict__ out)          // [B, N, H]
{
    __shared__ float tLds [NPB][16][TSTR];
    __shared__ float muLds[NPB][16];
    __shared__ float rsLds[NPB][16];

    const int tid  = threadIdx.x;
    const int wave = tid >> 6;
    const int lane = tid & 63;
    const int l16  = lane & 15;
    const int lg   = lane >> 4;      // 0..3

    const int ng   = blockIdx.x & 127;   // node group (minor: DRAM-span locality)
    const int rc   = blockIdx.x >> 7;    // 0..31 row chunk
    const int node = ng * NPB + wave;
    const int b0   = rc * RPB;

    const int   sc   = scales[node];
    const float sfac = dec[sc * 4 + 1] + rec[sc * 4 + 1];

    // ---- issue ALL W loads first (16 dwordx4/lane)
    f32x4 wv[4][2][2];
    const float* Wn = W + (size_t)node * HID * HID;
    #pragma unroll
    for (int c = 0; c < 4; ++c) {
        #pragma unroll
        for (int s = 0; s < 2; ++s) {
            const float* p = Wn + (c * 16 + l16) * HID + s * 32 + lg * 8;
            wv[c][s][0] = *reinterpret_cast<const f32x4*>(p);
            wv[c][s][1] = *reinterpret_cast<const f32x4*>(p + 4);
        }
    }

    // ---- then ALL x loads (16 dwordx4/lane), in flight behind W
    f32x4 xv[SUBS][4];
    #pragma unroll
    for (int sub = 0; sub < SUBS; ++sub) {
        const int row = b0 + sub * 16 + l16;
        const float* p = x + ((size_t)row * NNODES + node) * HID + lg * 8;
        xv[sub][0] = *reinterpret_cast<const f32x4*>(p);
        xv[sub][1] = *reinterpret_cast<const f32x4*>(p + 4);
        xv[sub][2] = *reinterpret_cast<const f32x4*>(p + 32);
        xv[sub][3] = *reinterpret_cast<const f32x4*>(p + 36);
    }

    // ---- epilogue params
    f32x4 bb[4];
    #pragma unroll
    for (int c = 0; c < 4; ++c)
        bb[c] = *reinterpret_cast<const f32x4*>(bias + node * HID + c * 16 + lg * 4);
    const f32x4 gg = *reinterpret_cast<const f32x4*>(gamma + node * HID + l16 * 4);
    const f32x4 be = *reinterpret_cast<const f32x4*>(beta  + node * HID + l16 * 4);

    // ---- convert W (its waitcnt leaves the x loads outstanding)
    bf16x8 wf[4][2];
    #pragma unroll
    for (int c = 0; c < 4; ++c) {
        #pragma unroll
        for (int s = 0; s < 2; ++s) {
            const f32x4 w0 = wv[c][s][0], w1 = wv[c][s][1];
            bf16x8 f;
            f[0] = f2bf(w0[0]); f[1] = f2bf(w0[1]); f[2] = f2bf(w0[2]); f[3] = f2bf(w0[3]);
            f[4] = f2bf(w1[0]); f[5] = f2bf(w1[1]); f[6] = f2bf(w1[2]); f[7] = f2bf(w1[3]);
            wf[c][s] = f;
        }
    }

    // ---- pin x loads above the compute (they are already issued; KEEP stops
    //      the compiler from sinking the loads to their first use)
    #pragma unroll
    for (int sub = 0; sub < SUBS; ++sub) {
        KEEP(xv[sub][0]); KEEP(xv[sub][1]); KEEP(xv[sub][2]); KEEP(xv[sub][3]);
    }

    #pragma unroll
    for (int sub = 0; sub < SUBS; ++sub) {
        const int rowb = b0 + sub * 16;

        bf16x8 af0, af1;
        {
            const f32x4 x0 = xv[sub][0], x1 = xv[sub][1];
            const f32x4 x2 = xv[sub][2], x3 = xv[sub][3];
            af0[0] = f2bf(x0[0] * sfac); af0[1] = f2bf(x0[1] * sfac);
            af0[2] = f2bf(x0[2] * sfac); af0[3] = f2bf(x0[3] * sfac);
            af0[4] = f2bf(x1[0] * sfac); af0[5] = f2bf(x1[1] * sfac);
            af0[6] = f2bf(x1[2] * sfac); af0[7] = f2bf(x1[3] * sfac);
            af1[0] = f2bf(x2[0] * sfac); af1[1] = f2bf(x2[1] * sfac);
            af1[2] = f2bf(x2[2] * sfac); af1[3] = f2bf(x2[3] * sfac);
            af1[4] = f2bf(x3[0] * sfac); af1[5] = f2bf(x3[1] * sfac);
            af1[6] = f2bf(x3[2] * sfac); af1[7] = f2bf(x3[3] * sfac);
        }

        f32x4 acc[4];
        #pragma unroll
        for (int c = 0; c < 4; ++c) {
            acc[c][0] = 0.f; acc[c][1] = 0.f; acc[c][2] = 0.f; acc[c][3] = 0.f;
            acc[c] = __builtin_amdgcn_mfma_f32_16x16x32_bf16(wf[c][0], af0, acc[c], 0, 0, 0);
            acc[c] = __builtin_amdgcn_mfma_f32_16x16x32_bf16(wf[c][1], af1, acc[c], 0, 0, 0);
        }

        // ---- +bias and two-pass LN stats in registers (R4/R6-verified)
        float pS = 0.f;
        #pragma unroll
        for (int c = 0; c < 4; ++c) {
            #pragma unroll
            for (int i = 0; i < 4; ++i) {
                acc[c][i] += bb[c][i];
                pS += acc[c][i];
            }
        }
        pS += __shfl_xor(pS, 16, 64);
        pS += __shfl_xor(pS, 32, 64);
        const float mu = pS * (1.0f / 64.0f);

        float qS = 0.f;
        #pragma unroll
        for (int c = 0; c < 4; ++c) {
            #pragma unroll
            for (int i = 0; i < 4; ++i) {
                const float d = acc[c][i] - mu;
                qS += d * d;
            }
        }
        qS += __shfl_xor(qS, 16, 64);
        qS += __shfl_xor(qS, 32, 64);
        const float rstd = 1.0f / sqrtf(qS * (1.0f / 64.0f) + LN_EPS);

        // ---- wave-private LDS repack (no cross-wave -> no barrier)
        #pragma unroll
        for (int c = 0; c < 4; ++c)
            *reinterpret_cast<f32x4*>(&tLds[wave][l16][c * 16 + lg * 4]) = acc[c];
        if (lg == 0) { muLds[wave][l16] = mu; rsLds[wave][l16] = rstd; }

        // ---- NT full-line stores: lane (l16,lg) -> row k*4+lg, cols l16*4..+3
        #pragma unroll
        for (int k = 0; k < 4; ++k) {
            const int rl = k * 4 + lg;
            f32x4 tv = *reinterpret_cast<const f32x4*>(&tLds[wave][rl][l16 * 4]);
            const float m  = muLds[wave][rl];
            const float rs = rsLds[wave][rl];
            f32x4 o;
            #pragma unroll
            for (int i = 0; i < 4; ++i) {
                float v = (tv[i] - m) * rs * gg[i] + be[i];
                o[i] = v >= 0.f ? v : v * NEG_SLOPE;
            }
            __builtin_nontemporal_store(
                o, reinterpret_cast<f32x4*>(
                       out + ((size_t)(rowb + rl) * NNODES + node) * HID + l16 * 4));
        }
    }
}

extern "C" void kernel_launch(void* const* d_in, const int* in_sizes, int n_in,
                              void* d_out, int out_size, void* d_ws, size_t ws_size,
                              hipStream_t stream) {
    const float* x      = (const float*)d_in[0];
    const float* dec    = (const float*)d_in[1];
    const float* rec    = (const float*)d_in[2];
    const float* W      = (const float*)d_in[3];
    const float* bias   = (const float*)d_in[4];
    const float* gamma  = (const float*)d_in[5];
    const float* beta   = (const float*)d_in[6];
    const int*   scales = (const int*)d_in[7];
    float* out = (float*)d_out;

    const int blocks = (NNODES / NPB) * (BATCH / RPB);  // 128 * 32 = 4096
    wv_mfma7_kernel<<<blocks, 256, 0, stream>>>(
        x, dec, rec, W, bias, gamma, beta, scales, out);
}

// Round 10
// 101.278 us; speedup vs baseline: 2.5342x; 2.0731x over previous
//
#include <hip/hip_runtime.h>
#include <hip/hip_bf16.h>

#define BATCH 2048
#define NNODES 512
#define HID 64
#define LN_EPS 1e-5f
#define NEG_SLOPE 0.01f

#define NPB 4        // nodes per block (one per wave; waves fully independent)
#define SUBS 8       // 16-row subtiles per wave
#define RPW 128      // rows per wave = SUBS*16
#define TSTR 68      // tLds row stride in floats

typedef __attribute__((ext_vector_type(8))) short bf16x8;
typedef __attribute__((ext_vector_type(4))) float f32x4;

__device__ __forceinline__ short f2bf(float f) {
    union { __hip_bfloat16 h; short s; } u;
    u.h = __float2bfloat16(f);   // canonical RNE (R3/R4-verified)
    return u.s;
}

#define WAITV4() asm volatile("s_waitcnt vmcnt(4)" ::: "memory")
#define WAITV8() asm volatile("s_waitcnt vmcnt(8)" ::: "memory")
#define WAITL0() asm volatile("s_waitcnt lgkmcnt(0)" ::: "memory")

// v10: R6-verified MFMA/LN/epilogue + two structural changes:
//  (1) 128 rows/wave: W load+convert once per 128 rows (W fabric 512->128MB)
//  (2) x staged via global_load_lds double-buffer (prefetch depth w/o VGPR
//      cost -> no spill, unlike R5/R9). Wave-private: no __syncthreads.
// Swizzle (rule #21, both-sides): gll dest is linear; global SOURCE float-idx
// is pre-swizzled by ^((row&7)<<2) (16B granule); ds_read applies same XOR ->
// 2-way banks only. vmcnt counted (stores retire in order too):
// N=4 at sub 0 / SUBS-1, else 8. lgkmcnt(0) before each stage guards the
// ds_read-vs-gll-overwrite race on the recycled buffer.
__global__ __launch_bounds__(256, 3) void wv_mfma8_kernel(
    const float* __restrict__ x,      // [B, N, H]
    const float* __restrict__ dec,    // [3, 4]
    const float* __restrict__ rec,    // [3, 4]
    const float* __restrict__ W,      // [N, H, H]
    const float* __restrict__ bias,   // [N, H]
    const float* __restrict__ gamma,  // [N, H]
    const float* __restrict__ beta,   // [N, H]
    const int*   __restrict__ scales, // [N]
    float* __restrict__ out)          // [B, N, H]
{
    __shared__ float xStage[NPB][2][1024];   // 2 x 4KB per wave, 32KB total
    __shared__ float tLds  [NPB][16][TSTR];
    __shared__ float muLds [NPB][16];
    __shared__ float rsLds [NPB][16];

    const int tid  = threadIdx.x;
    const int wave = tid >> 6;
    const int lane = tid & 63;
    const int l16  = lane & 15;
    const int lg   = lane >> 4;      // 0..3

    const int ng   = blockIdx.x & 127;   // node group minor (R7 lesson)
    const int rc   = blockIdx.x >> 7;    // 0..15 row chunk
    const int node = ng * NPB + wave;
    const int b0   = rc * RPW;

    const int   sc   = scales[node];
    const float sfac = dec[sc * 4 + 1] + rec[sc * 4 + 1];

// stage rows b0+(sub)*16..+15 into xStage[wave][buf]; lane j covers row
// k*4+(j>>4), 16B slot (j&15), source col pre-swizzled so LDS reads with the
// same XOR are bank-spread. 4 x global_load_lds_dwordx4 (1KB each).
#define STAGE(sub_, buf_)                                                     \
    {                                                                         \
        const int s4_ = (lane & 15) * 4;                                      \
        const int rb_ = lane >> 4;                                            \
        _Pragma("unroll")                                                     \
        for (int k_ = 0; k_ < 4; ++k_) {                                      \
            const int r_ = k_ * 4 + rb_;                                      \
            const float* g_ = x + (size_t)(b0 + (sub_) * 16 + r_) *           \
                                  (NNODES * HID) + node * HID +               \
                                  (s4_ ^ ((r_ & 7) << 2));                    \
            __builtin_amdgcn_global_load_lds(                                 \
                (const __attribute__((address_space(1))) void*)g_,            \
                (__attribute__((address_space(3))) void*)                     \
                    (&xStage[wave][buf_][0] + k_ * 256),                      \
                16, 0, 0);                                                    \
        }                                                                     \
    }

    // ---- prologue: W loads (16 dwordx4), then stage(0), stage(1)
    f32x4 wv[4][2][2];
    const float* Wn = W + (size_t)node * HID * HID;
    #pragma unroll
    for (int c = 0; c < 4; ++c) {
        #pragma unroll
        for (int s = 0; s < 2; ++s) {
            const float* p = Wn + (c * 16 + l16) * HID + s * 32 + lg * 8;
            wv[c][s][0] = *reinterpret_cast<const f32x4*>(p);
            wv[c][s][1] = *reinterpret_cast<const f32x4*>(p + 4);
        }
    }
    STAGE(0, 0);
    STAGE(1, 1);

    // ---- epilogue params
    f32x4 bb[4];
    #pragma unroll
    for (int c = 0; c < 4; ++c)
        bb[c] = *reinterpret_cast<const f32x4*>(bias + node * HID + c * 16 + lg * 4);
    const f32x4 gg = *reinterpret_cast<const f32x4*>(gamma + node * HID + l16 * 4);
    const f32x4 be = *reinterpret_cast<const f32x4*>(beta  + node * HID + l16 * 4);

    // ---- convert W once (compiler's own vmcnt wait covers the W loads)
    bf16x8 wf[4][2];
    #pragma unroll
    for (int c = 0; c < 4; ++c) {
        #pragma unroll
        for (int s = 0; s < 2; ++s) {
            const f32x4 w0 = wv[c][s][0], w1 = wv[c][s][1];
            bf16x8 f;
            f[0] = f2bf(w0[0]); f[1] = f2bf(w0[1]); f[2] = f2bf(w0[2]); f[3] = f2bf(w0[3]);
            f[4] = f2bf(w1[0]); f[5] = f2bf(w1[1]); f[6] = f2bf(w1[2]); f[7] = f2bf(w1[3]);
            wf[c][s] = f;
        }
    }

    const int ro = l16 * 64;           // LDS row offset (floats)
    const int sw = (l16 & 7) << 2;     // read-side XOR (floats)

    #pragma unroll
    for (int sub = 0; sub < SUBS; ++sub) {
        // counted wait: stage(sub) retired when <= N newer vmem ops remain
        if (sub == 0 || sub == SUBS - 1) { WAITV4(); } else { WAITV8(); }

        const float* Sb = &xStage[wave][sub & 1][0];
        const f32x4 x0 = *reinterpret_cast<const f32x4*>(Sb + ro + ((lg * 8     ) ^ sw));
        const f32x4 x1 = *reinterpret_cast<const f32x4*>(Sb + ro + ((lg * 8 + 4 ) ^ sw));
        const f32x4 x2 = *reinterpret_cast<const f32x4*>(Sb + ro + ((lg * 8 + 32) ^ sw));
        const f32x4 x3 = *reinterpret_cast<const f32x4*>(Sb + ro + ((lg * 8 + 36) ^ sw));

        bf16x8 af0, af1;
        af0[0] = f2bf(x0[0] * sfac); af0[1] = f2bf(x0[1] * sfac);
        af0[2] = f2bf(x0[2] * sfac); af0[3] = f2bf(x0[3] * sfac);
        af0[4] = f2bf(x1[0] * sfac); af0[5] = f2bf(x1[1] * sfac);
        af0[6] = f2bf(x1[2] * sfac); af0[7] = f2bf(x1[3] * sfac);
        af1[0] = f2bf(x2[0] * sfac); af1[1] = f2bf(x2[1] * sfac);
        af1[2] = f2bf(x2[2] * sfac); af1[3] = f2bf(x2[3] * sfac);
        af1[4] = f2bf(x3[0] * sfac); af1[5] = f2bf(x3[1] * sfac);
        af1[6] = f2bf(x3[2] * sfac); af1[7] = f2bf(x3[3] * sfac);

        f32x4 acc[4];
        #pragma unroll
        for (int c = 0; c < 4; ++c) {
            acc[c][0] = 0.f; acc[c][1] = 0.f; acc[c][2] = 0.f; acc[c][3] = 0.f;
            acc[c] = __builtin_amdgcn_mfma_f32_16x16x32_bf16(wf[c][0], af0, acc[c], 0, 0, 0);
            acc[c] = __builtin_amdgcn_mfma_f32_16x16x32_bf16(wf[c][1], af1, acc[c], 0, 0, 0);
        }

        // ---- +bias, two-pass LN in registers (R4/R6-verified)
        float pS = 0.f;
        #pragma unroll
        for (int c = 0; c < 4; ++c) {
            #pragma unroll
            for (int i = 0; i < 4; ++i) {
                acc[c][i] += bb[c][i];
                pS += acc[c][i];
            }
        }
        pS += __shfl_xor(pS, 16, 64);
        pS += __shfl_xor(pS, 32, 64);
        const float mu = pS * (1.0f / 64.0f);

        float qS = 0.f;
        #pragma unroll
        for (int c = 0; c < 4; ++c) {
            #pragma unroll
            for (int i = 0; i < 4; ++i) {
                const float d = acc[c][i] - mu;
                qS += d * d;
            }
        }
        qS += __shfl_xor(qS, 16, 64);
        qS += __shfl_xor(qS, 32, 64);
        const float rstd = 1.0f / sqrtf(qS * (1.0f / 64.0f) + LN_EPS);

        // ---- wave-private LDS repack (no barrier)
        #pragma unroll
        for (int c = 0; c < 4; ++c)
            *reinterpret_cast<f32x4*>(&tLds[wave][l16][c * 16 + lg * 4]) = acc[c];
        if (lg == 0) { muLds[wave][l16] = mu; rsLds[wave][l16] = rstd; }

        // ---- NT full-line stores: lane (l16,lg) -> row k*4+lg, cols l16*4..+3
        const int rowb = b0 + sub * 16;
        #pragma unroll
        for (int k = 0; k < 4; ++k) {
            const int rl = k * 4 + lg;
            f32x4 tv = *reinterpret_cast<const f32x4*>(&tLds[wave][rl][l16 * 4]);
            const float m  = muLds[wave][rl];
            const float rs = rsLds[wave][rl];
            f32x4 o;
            #pragma unroll
            for (int i = 0; i < 4; ++i) {
                float v = (tv[i] - m) * rs * gg[i] + be[i];
                o[i] = v >= 0.f ? v : v * NEG_SLOPE;
            }
            __builtin_nontemporal_store(
                o, reinterpret_cast<f32x4*>(
                       out + ((size_t)(rowb + rl) * NNODES + node) * HID + l16 * 4));
        }

        // ---- recycle this sub's buffer: ensure its ds_reads retired, then
        //      prefetch sub+2 into it
        WAITL0();
        if (sub + 2 < SUBS) {
            STAGE(sub + 2, sub & 1);
        }
    }
#undef STAGE
}

extern "C" void kernel_launch(void* const* d_in, const int* in_sizes, int n_in,
                              void* d_out, int out_size, void* d_ws, size_t ws_size,
                              hipStream_t stream) {
    const float* x      = (const float*)d_in[0];
    const float* dec    = (const float*)d_in[1];
    const float* rec    = (const float*)d_in[2];
    const float* W      = (const float*)d_in[3];
    const float* bias   = (const float*)d_in[4];
    const float* gamma  = (const float*)d_in[5];
    const float* beta   = (const float*)d_in[6];
    const int*   scales = (const int*)d_in[7];
    float* out = (float*)d_out;

    const int blocks = (NNODES / NPB) * (BATCH / RPW);  // 128 * 16 = 2048
    wv_mfma8_kernel<<<blocks, 256, 0, stream>>>(
        x, dec, rec, W, bias, gamma, beta, scales, out);
}